// Round 2
// baseline (61.699 us; speedup 1.0000x reference)
//
#include <hip/hip_runtime.h>
#include <math.h>

// MAM "FullyConnected": C[n,m] = max_k(x[n,k]*w[m,k]) + min_k(...) + bias[m]
// plus argmax/argmin. N=1024, M=512, K=512, all f32.
// Outputs concatenated in d_out: C | argmax | argmin (each N*M elements).
// NOTE: harness reads the whole d_out as float32 -> indices stored as floats.

constexpr int NTOT = 1024;
constexpr int MTOT = 512;
constexpr int KTOT = 512;
constexpr int BN = 32;    // output rows per block
constexpr int BM = 32;    // output cols per block
constexpr int BK = 128;   // k-chunk staged in LDS
constexpr int LDSP = BK + 4;  // 132: keeps 16B row alignment, breaks 32-bank aliasing to 2-way (free)

// branchless extremum update; strict compare keeps FIRST occurrence (matches jnp.argmax/argmin)
#define UPDATE(PEXPR, S)                                        \
  {                                                             \
    const float p_ = (PEXPR);                                   \
    const bool g_ = p_ > vmax##S;                               \
    vmax##S = g_ ? p_ : vmax##S;                                \
    imax##S = g_ ? k : imax##S;                                 \
    const bool l_ = p_ < vmin##S;                               \
    vmin##S = l_ ? p_ : vmin##S;                                \
    imin##S = l_ ? k : imin##S;                                 \
  }

__global__ __launch_bounds__(256) void mam_kernel(
    const float* __restrict__ X,   // [NTOT][KTOT]
    const float* __restrict__ W,   // [MTOT][KTOT]
    const float* __restrict__ B,   // [MTOT]
    float* __restrict__ out)       // C | argmax | argmin (all read back as f32)
{
  __shared__ float sx[BN][LDSP];
  __shared__ float sw[BM][LDSP];

  const int t  = threadIdx.x;
  const int bm = blockIdx.x;          // 0..15
  const int bn = blockIdx.y;          // 0..31
  const int n0 = bn * BN;
  const int m0 = bm * BM;

  const int tn = t >> 4;              // 0..15
  const int tm = t & 15;              // 0..15
  const int r0 = tn, r1 = tn + 16;    // output rows within tile
  const int c0 = tm, c1 = tm + 16;    // output cols within tile

  float vmax00 = -INFINITY, vmax01 = -INFINITY, vmax10 = -INFINITY, vmax11 = -INFINITY;
  float vmin00 =  INFINITY, vmin01 =  INFINITY, vmin10 =  INFINITY, vmin11 =  INFINITY;
  int   imax00 = 0, imax01 = 0, imax10 = 0, imax11 = 0;
  int   imin00 = 0, imin01 = 0, imin10 = 0, imin11 = 0;

  for (int kc = 0; kc < KTOT; kc += BK) {
    __syncthreads();  // protect LDS from previous iteration's readers
    // stage x-tile [BN][BK] and w-tile [BM][BK]: 4096 floats each, float4 loads
    #pragma unroll
    for (int j = 0; j < 4; ++j) {
      const int idx = t + 256 * j;     // 0..1023
      const int r = idx >> 5;          // 0..31 (row within tile)
      const int f = idx & 31;          // float4 index within 128-float row
      const float4 vx = *reinterpret_cast<const float4*>(&X[(n0 + r) * KTOT + kc + f * 4]);
      *reinterpret_cast<float4*>(&sx[r][f * 4]) = vx;
      const float4 vw = *reinterpret_cast<const float4*>(&W[(m0 + r) * KTOT + kc + f * 4]);
      *reinterpret_cast<float4*>(&sw[r][f * 4]) = vw;
    }
    __syncthreads();

    #pragma unroll 8
    for (int kk = 0; kk < BK; ++kk) {
      const int k = kc + kk;
      const float x0 = sx[r0][kk];
      const float x1 = sx[r1][kk];
      const float w0 = sw[c0][kk];
      const float w1 = sw[c1][kk];
      UPDATE(x0 * w0, 00)
      UPDATE(x0 * w1, 01)
      UPDATE(x1 * w0, 10)
      UPDATE(x1 * w1, 11)
    }
  }

  // epilogue: C = vmax + vmin + bias; indices written as FLOAT values
  float* Cout = out;
  float* AM   = out + NTOT * MTOT;       // argmax (as f32 values)
  float* AN   = AM + NTOT * MTOT;        // argmin (as f32 values)

  const float b0 = B[m0 + c0];
  const float b1 = B[m0 + c1];

  const int o00 = (n0 + r0) * MTOT + (m0 + c0);
  const int o01 = (n0 + r0) * MTOT + (m0 + c1);
  const int o10 = (n0 + r1) * MTOT + (m0 + c0);
  const int o11 = (n0 + r1) * MTOT + (m0 + c1);

  Cout[o00] = vmax00 + vmin00 + b0;  AM[o00] = (float)imax00;  AN[o00] = (float)imin00;
  Cout[o01] = vmax01 + vmin01 + b1;  AM[o01] = (float)imax01;  AN[o01] = (float)imin01;
  Cout[o10] = vmax10 + vmin10 + b0;  AM[o10] = (float)imax10;  AN[o10] = (float)imin10;
  Cout[o11] = vmax11 + vmin11 + b1;  AM[o11] = (float)imax11;  AN[o11] = (float)imin11;
}

extern "C" void kernel_launch(void* const* d_in, const int* in_sizes, int n_in,
                              void* d_out, int out_size, void* d_ws, size_t ws_size,
                              hipStream_t stream) {
  const float* X = (const float*)d_in[0];   // [8,128,512] -> [1024][512]
  const float* W = (const float*)d_in[1];   // [512][512]
  const float* B = (const float*)d_in[2];   // [512]
  float* out = (float*)d_out;

  dim3 grid(MTOT / BM, NTOT / BN);          // (16, 32) = 512 blocks
  mam_kernel<<<grid, dim3(256), 0, stream>>>(X, W, B, out);
}

// Round 3
// 59.649 us; speedup vs baseline: 1.0344x; 1.0344x over previous
//
#include <hip/hip_runtime.h>
#include <math.h>

// MAM "FullyConnected": C[n,m] = max_k(x[n,k]*w[m,k]) + min_k(...) + bias[m]
// plus argmax/argmin (first occurrence). N=1024, M=512, K=512, f32.
// d_out (read back as f32): C | argmax | argmin, each N*M.

constexpr int NTOT = 1024;
constexpr int MTOT = 512;
constexpr int KTOT = 512;
constexpr int BN = 32;        // output rows per block
constexpr int BM = 32;        // output cols per block
constexpr int BK = 128;       // k-chunk staged in LDS
constexpr int LDSP = BK + 4;  // 132 floats: 16B-aligned rows; sw col-read is 4-way aliased (cheap, hidden)

// branchless; strict compare keeps FIRST occurrence (matches jnp.argmax/argmin)
#define UPD(XX, WW, KK, S)                  \
  {                                         \
    const float p_ = (XX) * (WW);           \
    const bool g_ = p_ > vmax##S;           \
    vmax##S = g_ ? p_ : vmax##S;            \
    imax##S = g_ ? (KK) : imax##S;          \
    const bool l_ = p_ < vmin##S;           \
    vmin##S = l_ ? p_ : vmin##S;            \
    imin##S = l_ ? (KK) : imin##S;          \
  }

__global__ __launch_bounds__(512, 4) void mam_kernel(
    const float* __restrict__ X,   // [NTOT][KTOT]
    const float* __restrict__ W,   // [MTOT][KTOT]
    const float* __restrict__ B,   // [MTOT]
    float* __restrict__ out)
{
  __shared__ float sx[BN][LDSP];
  __shared__ float sw[BM][LDSP];

  const int t  = threadIdx.x;          // 0..511
  const int n0 = blockIdx.y * BN;
  const int m0 = blockIdx.x * BM;

  const int tn = t >> 5;               // 0..15
  const int c0 = t & 31;               // 0..31  (col within tile)
  const int r0 = tn, r1 = tn + 16;     // two rows within tile

  float vmax0 = -INFINITY, vmax1 = -INFINITY;
  float vmin0 =  INFINITY, vmin1 =  INFINITY;
  int   imax0 = 0, imax1 = 0, imin0 = 0, imin1 = 0;

  for (int kc = 0; kc < KTOT; kc += BK) {
    __syncthreads();  // protect LDS from previous iteration's readers
    // stage x[32][128] and w[32][128]: 1024 float4 each, 512 threads -> 2 each
    #pragma unroll
    for (int j = 0; j < 2; ++j) {
      const int id = t + 512 * j;      // 0..1023
      const int r  = id >> 5;          // 0..31
      const int f  = id & 31;          // float4 slot within row
      *reinterpret_cast<float4*>(&sx[r][f * 4]) =
          *reinterpret_cast<const float4*>(&X[(n0 + r) * KTOT + kc + f * 4]);
      *reinterpret_cast<float4*>(&sw[r][f * 4]) =
          *reinterpret_cast<const float4*>(&W[(m0 + r) * KTOT + kc + f * 4]);
    }
    __syncthreads();

    #pragma unroll 8
    for (int q = 0; q < BK / 4; ++q) {
      const float4 xa = *reinterpret_cast<const float4*>(&sx[r0][q * 4]);
      const float4 xb = *reinterpret_cast<const float4*>(&sx[r1][q * 4]);
      const float4 wa = *reinterpret_cast<const float4*>(&sw[c0][q * 4]);
      const int kb = kc + q * 4;
      UPD(xa.x, wa.x, kb + 0, 0)
      UPD(xa.y, wa.y, kb + 1, 0)
      UPD(xa.z, wa.z, kb + 2, 0)
      UPD(xa.w, wa.w, kb + 3, 0)
      UPD(xb.x, wa.x, kb + 0, 1)
      UPD(xb.y, wa.y, kb + 1, 1)
      UPD(xb.z, wa.z, kb + 2, 1)
      UPD(xb.w, wa.w, kb + 3, 1)
    }
  }

  // epilogue: C = vmax + vmin + bias; indices as FLOAT values (harness reads f32)
  float* Cout = out;
  float* AM   = out + NTOT * MTOT;
  float* AN   = AM + NTOT * MTOT;

  const float b = B[m0 + c0];
  const int o0 = (n0 + r0) * MTOT + (m0 + c0);
  const int o1 = (n0 + r1) * MTOT + (m0 + c0);

  Cout[o0] = vmax0 + vmin0 + b;  AM[o0] = (float)imax0;  AN[o0] = (float)imin0;
  Cout[o1] = vmax1 + vmin1 + b;  AM[o1] = (float)imax1;  AN[o1] = (float)imin1;
}

extern "C" void kernel_launch(void* const* d_in, const int* in_sizes, int n_in,
                              void* d_out, int out_size, void* d_ws, size_t ws_size,
                              hipStream_t stream) {
  const float* X = (const float*)d_in[0];   // [8,128,512] -> [1024][512]
  const float* W = (const float*)d_in[1];   // [512][512]
  const float* B = (const float*)d_in[2];   // [512]
  float* out = (float*)d_out;

  dim3 grid(MTOT / BM, NTOT / BN);          // (16, 32) = 512 blocks
  mam_kernel<<<grid, dim3(512), 0, stream>>>(X, W, B, out);
}

// Round 4
// 58.373 us; speedup vs baseline: 1.0570x; 1.0219x over previous
//
#include <hip/hip_runtime.h>
#include <math.h>

// MAM "FullyConnected": C[n,m] = max_k(x[n,k]*w[m,k]) + min_k(...) + bias[m]
// plus argmax/argmin (first occurrence). N=1024, M=512, K=512, f32.
// d_out (read back as f32): C | argmax | argmin, each N*M.
//
// Round 4: 7-VALU-op/product inner form (inverted cmp + cndmask w/ uniform k
// in src0 + v_max/v_min for values), 16x16 tiles, 2048 blocks = 8/CU for full
// wave occupancy (prev round was grid-limited at 2 blocks/CU, 32% occupancy).

constexpr int NTOT = 1024;
constexpr int MTOT = 512;
constexpr int KTOT = 512;
constexpr int BN = 16;        // output rows per block
constexpr int BM = 16;        // output cols per block
constexpr int BK = 128;       // k-chunk staged in LDS
constexpr int LDSP = BK + 4;  // 132 floats: 16B-aligned rows; col-reads 2-way aliased (free per m136)

__global__ __launch_bounds__(256, 8) void mam_kernel(
    const float* __restrict__ X,   // [NTOT][KTOT]
    const float* __restrict__ W,   // [MTOT][KTOT]
    const float* __restrict__ B,   // [MTOT]
    float* __restrict__ out)
{
  __shared__ float sx[BN][LDSP];
  __shared__ float sw[BM][LDSP];

  const int t  = threadIdx.x;          // 0..255
  const int n0 = blockIdx.y * BN;
  const int m0 = blockIdx.x * BM;

  const int r0 = t >> 4;               // 0..15 row within tile
  const int c0 = t & 15;               // 0..15 col within tile

  float vmax = -INFINITY, vmin = INFINITY;
  int   imax = 0, imin = 0;

  #pragma unroll 1
  for (int kc = 0; kc < KTOT; kc += BK) {
    __syncthreads();  // protect LDS from previous iteration's readers
    // stage x[16][128] and w[16][128]: 512 float4 each, 256 threads -> 2 each
    #pragma unroll
    for (int j = 0; j < 2; ++j) {
      const int id = t + 256 * j;      // 0..511
      const int r  = id >> 5;          // 0..15
      const int f  = id & 31;          // float4 slot within 128-float row
      *reinterpret_cast<float4*>(&sx[r][f * 4]) =
          *reinterpret_cast<const float4*>(&X[(n0 + r) * KTOT + kc + f * 4]);
      *reinterpret_cast<float4*>(&sw[r][f * 4]) =
          *reinterpret_cast<const float4*>(&W[(m0 + r) * KTOT + kc + f * 4]);
    }
    __syncthreads();

    #pragma unroll
    for (int q = 0; q < BK / 4; ++q) {
      const float4 xv = *reinterpret_cast<const float4*>(&sx[r0][q * 4]);
      const float4 wv = *reinterpret_cast<const float4*>(&sw[c0][q * 4]);
      const int kb = kc + q * 4;       // wave-uniform (SALU)
      {
        const float p = xv.x * wv.x;
        imax = (p <= vmax) ? imax : (kb + 0);  vmax = fmaxf(vmax, p);
        imin = (p >= vmin) ? imin : (kb + 0);  vmin = fminf(vmin, p);
      }
      {
        const float p = xv.y * wv.y;
        imax = (p <= vmax) ? imax : (kb + 1);  vmax = fmaxf(vmax, p);
        imin = (p >= vmin) ? imin : (kb + 1);  vmin = fminf(vmin, p);
      }
      {
        const float p = xv.z * wv.z;
        imax = (p <= vmax) ? imax : (kb + 2);  vmax = fmaxf(vmax, p);
        imin = (p >= vmin) ? imin : (kb + 2);  vmin = fminf(vmin, p);
      }
      {
        const float p = xv.w * wv.w;
        imax = (p <= vmax) ? imax : (kb + 3);  vmax = fmaxf(vmax, p);
        imin = (p >= vmin) ? imin : (kb + 3);  vmin = fminf(vmin, p);
      }
    }
  }

  // epilogue: C = vmax + vmin + bias; indices as FLOAT values (harness reads f32)
  float* Cout = out;
  float* AM   = out + NTOT * MTOT;
  float* AN   = AM + NTOT * MTOT;

  const int o = (n0 + r0) * MTOT + (m0 + c0);
  Cout[o] = vmax + vmin + B[m0 + c0];
  AM[o]   = (float)imax;
  AN[o]   = (float)imin;
}

extern "C" void kernel_launch(void* const* d_in, const int* in_sizes, int n_in,
                              void* d_out, int out_size, void* d_ws, size_t ws_size,
                              hipStream_t stream) {
  const float* X = (const float*)d_in[0];   // [8,128,512] -> [1024][512]
  const float* W = (const float*)d_in[1];   // [512][512]
  const float* B = (const float*)d_in[2];   // [512]
  float* out = (float*)d_out;

  dim3 grid(MTOT / BM, NTOT / BN);          // (32, 64) = 2048 blocks = 8/CU
  mam_kernel<<<grid, dim3(256), 0, stream>>>(X, W, B, out);
}